// Round 3
// baseline (114.424 us; speedup 1.0000x reference)
//
#include <hip/hip_runtime.h>

// ---------------------------------------------------------------------------
// Output depends ONLY on positions[0:64]. ~14M MACs total.
//
// R11: ONE kernel + 2 spin barriers (counters in ws, zeroed by a captured
// hipMemsetAsync). R10 showed dispatch boundaries are ~free; the lever is
// kernel time itself, dominated by CD's serial 392KB-per-CU staging on 4 CUs.
// New structure (64 blocks x 256 thr, 1 block/CU, statics 29KB + dyn 128KB):
//  - All blocks: A phase (bg=blk>>3, x8 replicated) + B phase (j0=(blk&7)*32)
//    VERBATIM from R10 -> tpart_ws; release-add cnt0.
//  - Blocks 8..39: pre-stage Wn2 8-col slice (8KB) into freed sm BEFORE the
//    barrier; spin cnt0==64; stage tpart; tbar + 8 agg outputs (verbatim
//    per-output chunk order, slice is 8-wide) -> agg_ws; release-add cnt1.
//  - Blocks 0..3: stage Wh1[k] (128KB) into sm right after B (overlaps the
//    whole agg phase); spin cnt1==32; read agg_ws; heads + dot VERBATIM.
//  - Other blocks exit after release-add.
// Spins are bounded (no hang if residency assumption breaks). NO cooperative
// launch (R9 lesson). 64 blocks <= 256 CUs -> co-resident.
//
// BIT-EXACTNESS: harness demands bit-exact (R1 failed by one ulp). Every
// per-output accumulation keeps the VERBATIM expression structure and
// ascending chunk order from rounds that scored absmax 0.0. agg values
// round-trip through f32 global losslessly. Do not reassociate.
// ---------------------------------------------------------------------------

__device__ __forceinline__ void async_cp16(const float* g, float* l) {
    __builtin_amdgcn_global_load_lds(
        (const __attribute__((address_space(1))) void*)g,
        (__attribute__((address_space(3))) void*)l, 16, 0, 0);
}
// contiguous: nfloats multiple of 256; 1 inst moves 256 floats (64 lanes x 16B)
__device__ __forceinline__ void stage_contig(const float* g, float* l, int nfloats, int tid) {
    const int lane = tid & 63, wv = tid >> 6;
    const int ninst = nfloats >> 8;
    for (int i = wv; i < ninst; i += 4)
        async_cp16(g + i*256 + lane*4, l + i*256);
}
// 32-col slice of row-major [nrows][ld] at col j0 -> LDS [r][32]
__device__ __forceinline__ void stage_slice32(const float* g, float* l, int ld, int j0, int nrows, int tid) {
    const int lane = tid & 63, wv = tid >> 6;
    const int r = lane >> 3, c4 = (lane & 7) << 2;
    const int ninst = nrows >> 3;
    for (int i = wv; i < ninst; i += 4)
        async_cp16(g + (i*8 + r)*ld + j0 + c4, l + i*256);
}

#define F_SMEM_BYTES (32768*4)   // 128 KB dynamic: W3 -> Wn1 slice -> Wn2 slice / Wh1[k]

__global__ __launch_bounds__(256) void fused_all(
    const float* __restrict__ positions, const float* __restrict__ grid_pts,
    const float* __restrict__ W1, const float* __restrict__ b1,
    const float* __restrict__ W2, const float* __restrict__ b2,
    const float* __restrict__ W3, const float* __restrict__ b3,
    const float* __restrict__ Wn1, const float* __restrict__ bn1,
    const float* __restrict__ Wn2, const float* __restrict__ bn2,
    const float* __restrict__ Wh1, const float* __restrict__ bh1,
    const float* __restrict__ Wh2, const float* __restrict__ bh2,
    float* __restrict__ tpart_ws,                           // (8,256)
    float* __restrict__ agg_ws,                             // (256)
    unsigned int* __restrict__ cnts,                        // [2], zeroed pre-launch
    float* __restrict__ out)                                // (4)
{
    extern __shared__ float sm[];                           // 128 KB dynamic
    __shared__ float pos_s[192], grid_s[192], w1_s[192], b1_s[64];
    __shared__ int   idx_s[64], win_s[8];
    __shared__ __align__(16) float h1s[8*64];
    __shared__ __align__(16) float h2s[8*128];
    __shared__ __align__(16) float gf_s[8*256];
    __shared__ float r_s[256];
    __shared__ __align__(16) float tp_s[2048];
    __shared__ __align__(16) float tbar_s[256];
    __shared__ __align__(16) float agg_s[256];
    __shared__ __align__(16) float h1h_s[128];
    __shared__ __align__(16) float wh2_s[128];

    const int tid = threadIdx.x;
    const int blk = blockIdx.x;
    const int bg  = blk >> 3;          // rows bg*8 .. bg*8+7 (replicated x8)

    // ===================== A phase (verbatim a_gf) =========================
    stage_contig(W3, sm, 32768, tid);                       // async at entry
    if (tid < 192) { pos_s[tid] = positions[tid]; grid_s[tid] = grid_pts[tid]; w1_s[tid] = W1[tid]; }
    if (tid >= 192) b1_s[tid - 192] = b1[tid - 192];
    const float bb2 = b2[tid & 127];
    const float bb3 = b3[tid];
    __syncthreads();                                        // ONE drain

    if (tid < 64) {                      // verbatim argmin
        const float px = pos_s[tid*3], py = pos_s[tid*3+1], pz = pos_s[tid*3+2];
        float best = 3.4e38f; int bi = 0;
        for (int g = 0; g < 64; ++g) {
            const float dx = px - grid_s[g*3];
            const float dy = py - grid_s[g*3+1];
            const float dz = pz - grid_s[g*3+2];
            const float d2 = dx*dx + dy*dy + dz*dz;
            if (d2 < best) { best = d2; bi = g; }
        }
        idx_s[tid] = bi;
    }
    __syncthreads();
    if (tid < 8) {                       // verbatim winner rule, own 8 rows
        const int g = bg*8 + tid;
        int m = -1;
        for (int i = 0; i < 64; ++i) if (idx_s[i] == g) m = i;
        win_s[tid] = m;
    }
    __syncthreads();

    // h1 own 8 rows (512 outs): verbatim expression
    #pragma unroll
    for (int u = 0; u < 2; ++u) {
        const int e  = tid + u*256;
        const int lr = e >> 6, kk = e & 63;
        int r = win_s[lr]; if (r < 0) r = 0;
        const float acc = b1_s[kk] + pos_s[r*3]*w1_s[kk] + pos_s[r*3+1]*w1_s[64+kk]
                                   + pos_s[r*3+2]*w1_s[128+kk];
        h1s[lr*64 + kk] = fmaxf(acc, 0.f);
    }
    __syncthreads();

    // h2 own 8 rows: verbatim chunk structure; W2 via chunked GLOBAL loads
    {
        const int d = tid & 127, t0 = tid >> 7;
        float acc[4];
        #pragma unroll
        for (int m = 0; m < 4; ++m) acc[m] = bb2;
        for (int kc = 0; kc < 64; kc += 16) {
            float w[16];
            #pragma unroll
            for (int u = 0; u < 16; ++u) w[u] = W2[(kc+u)*128 + d];
            #pragma unroll
            for (int u = 0; u < 16; u += 4) {
                #pragma unroll
                for (int m = 0; m < 4; ++m) {
                    const float4 h4 = *(const float4*)&h1s[(t0 + 2*m)*64 + kc + u];
                    acc[m] += h4.x*w[u] + h4.y*w[u+1] + h4.z*w[u+2] + h4.w*w[u+3];
                }
            }
        }
        #pragma unroll
        for (int m = 0; m < 4; ++m)
            h2s[(t0 + 2*m)*128 + d] = fmaxf(acc[m], 0.f);
    }
    __syncthreads();

    // gf own 8 rows x all 256 cols: verbatim accumulation, W3 from LDS (sm)
    {
        const int j = tid;
        float ag[8];
        #pragma unroll
        for (int t = 0; t < 8; ++t) ag[t] = 0.f;
        for (int dc = 0; dc < 128; dc += 16) {
            float w[16];
            #pragma unroll
            for (int u = 0; u < 16; ++u) w[u] = sm[(dc+u)*256 + j];
            #pragma unroll
            for (int u = 0; u < 16; u += 4) {
                #pragma unroll
                for (int t = 0; t < 8; ++t) {
                    const float4 h4 = *(const float4*)&h2s[t*128 + dc + u];
                    ag[t] += h4.x*w[u] + h4.y*w[u+1] + h4.z*w[u+2] + h4.w*w[u+3];
                }
            }
        }
        #pragma unroll
        for (int t = 0; t < 8; ++t)
            gf_s[t*256 + j] = (win_s[t] >= 0) ? (ag[t] + bb3) : 0.f;
    }
    __syncthreads();                     // gf_s ready; sm (W3) now free

    // ===================== B phase (verbatim k2_tpart) =====================
    {
        const int j0 = (blk & 7) * 32;
        stage_slice32(Wn1, sm, 256, j0, 256, tid);          // same [row][32] layout
        const int jl = tid & 31, t = tid >> 5;
        const float bb = bn1[j0 + jl];
        __syncthreads();                                    // drain slice

        float acc = bb;
        for (int cc = 0; cc < 256; cc += 32) {
            float w[32];
            #pragma unroll
            for (int u = 0; u < 32; ++u) w[u] = sm[(cc+u)*32 + jl];
            #pragma unroll
            for (int u = 0; u < 32; u += 4) {
                const float4 g4 = *(const float4*)&gf_s[t*256 + cc + u];
                acc += g4.x*w[u] + g4.y*w[u+1] + g4.z*w[u+2] + g4.w*w[u+3];
            }
        }
        r_s[tid] = fmaxf(acc, 0.f);
        __syncthreads();                 // sm (Wn1 slice) now free
        if (t == 0) {
            float ps = 0.f;
            #pragma unroll
            for (int tt = 0; tt < 8; ++tt) ps += r_s[tt*32 + jl];
            tpart_ws[bg*256 + j0 + jl] = ps;
        }
    }

    // ============ role-based early staging (overlaps barrier skew) =========
    const bool is_head = (blk < 4);
    const bool is_agg  = (blk >= 8 && blk < 40);
    if (is_head) {
        stage_contig(Wh1 + blk*32768, sm, 32768, tid);      // full Wh1[k], 128 KB
        if (tid < 128) wh2_s[tid] = Wh2[blk*128 + tid];
    } else if (is_agg) {
        // Wn2 col-slice [256 rows][8 cols] at j0a -> sm[r*8 + c]
        const int j0a = (blk - 8) * 8;
        const int lane = tid & 63, wv = tid >> 6;
        const int r = lane >> 1, c4 = (lane & 1) << 2;
        for (int i = wv; i < 8; i += 4)
            async_cp16(Wn2 + (i*32 + r)*256 + j0a + c4, sm + i*256);
    }
    __syncthreads();                     // drains tpart stores (vmcnt 0)
    if (tid == 0)
        __hip_atomic_fetch_add(&cnts[0], 1u, __ATOMIC_RELEASE, __HIP_MEMORY_SCOPE_AGENT);

    // ===================== agg phase (blocks 8..39) ========================
    if (is_agg) {
        if (tid == 0) {
            unsigned guard = 0;
            while (__hip_atomic_load(&cnts[0], __ATOMIC_ACQUIRE, __HIP_MEMORY_SCOPE_AGENT) < 64u) {
                if (++guard > (1u << 24)) break;            // bounded: no hang
            }
        }
        __syncthreads();                 // all threads see barrier passed
        stage_contig(tpart_ws, tp_s, 2048, tid);
        __syncthreads();                 // drain tp + Wn2 slice

        {   // tbar: verbatim (q ascending, then *1/64)
            float tb = 0.f;
            #pragma unroll
            for (int q = 0; q < 8; ++q) tb += tp_s[q*256 + tid];
            tbar_s[tid] = tb * (1.f/64.f);
        }
        __syncthreads();

        if (tid < 8) {   // agg outputs j0a..j0a+7: verbatim chunk order
            const int j0a = (blk - 8) * 8;
            float acc = bn2[j0a + tid];
            for (int jc = 0; jc < 256; jc += 32) {
                float w[32];
                #pragma unroll
                for (int u = 0; u < 32; ++u) w[u] = sm[(jc+u)*8 + tid];
                #pragma unroll
                for (int u = 0; u < 32; u += 4) {
                    const float4 t4 = *(const float4*)&tbar_s[jc + u];
                    acc += t4.x*w[u] + t4.y*w[u+1] + t4.z*w[u+2] + t4.w*w[u+3];
                }
            }
            agg_ws[j0a + tid] = acc;
        }
        __syncthreads();                 // drain agg stores before release
        if (tid == 0)
            __hip_atomic_fetch_add(&cnts[1], 1u, __ATOMIC_RELEASE, __HIP_MEMORY_SCOPE_AGENT);
        return;
    }
    if (!is_head) return;

    // ===================== heads phase (blocks 0..3) =======================
    const int k = blk;
    const float bbh1k = (tid < 128) ? bh1[k*128 + tid] : 0.f;
    const float bbh2k = bh2[k];
    if (tid == 0) {
        unsigned guard = 0;
        while (__hip_atomic_load(&cnts[1], __ATOMIC_ACQUIRE, __HIP_MEMORY_SCOPE_AGENT) < 32u) {
            if (++guard > (1u << 24)) break;                // bounded: no hang
        }
    }
    __syncthreads();                     // also drains Wh1 staging (vmcnt 0)
    agg_s[tid] = agg_ws[tid];
    __syncthreads();

    float* bufA = sm;            // Wh1[k] rows 0..127
    float* bufB = sm + 16384;    // rows 128..255

    if (tid < 128) {   // heads: verbatim chunk structure, cc ascending
        const int d = tid;
        float a = bbh1k;
        for (int cc = 0; cc < 128; cc += 16) {
            float wa[16];
            #pragma unroll
            for (int u = 0; u < 16; ++u) wa[u] = bufA[(cc+u)*128 + d];
            #pragma unroll
            for (int u = 0; u < 16; u += 4) {
                const float4 a4 = *(const float4*)&agg_s[cc + u];
                a += a4.x*wa[u] + a4.y*wa[u+1] + a4.z*wa[u+2] + a4.w*wa[u+3];
            }
        }
        for (int cc = 128; cc < 256; cc += 16) {
            float wa[16];
            #pragma unroll
            for (int u = 0; u < 16; ++u) wa[u] = bufB[(cc-128+u)*128 + d];
            #pragma unroll
            for (int u = 0; u < 16; u += 4) {
                const float4 a4 = *(const float4*)&agg_s[cc + u];
                a += a4.x*wa[u] + a4.y*wa[u+1] + a4.z*wa[u+2] + a4.w*wa[u+3];
            }
        }
        h1h_s[d] = fmaxf(a, 0.f);
    }
    __syncthreads();
    if (tid == 0) {    // verbatim strictly-sequential final dot
        float a = bbh2k;
        for (int d = 0; d < 128; ++d) a += h1h_s[d] * wh2_s[d];
        out[k] = a;
    }
}

extern "C" void kernel_launch(void* const* d_in, const int* in_sizes, int n_in,
                              void* d_out, int out_size, void* d_ws, size_t ws_size,
                              hipStream_t stream) {
    const float* positions = (const float*)d_in[0];
    const float* grid      = (const float*)d_in[1];
    const float* W1  = (const float*)d_in[2];
    const float* b1  = (const float*)d_in[3];
    const float* W2  = (const float*)d_in[4];
    const float* b2  = (const float*)d_in[5];
    const float* W3  = (const float*)d_in[6];
    const float* b3  = (const float*)d_in[7];
    const float* Wn1 = (const float*)d_in[8];
    const float* bn1 = (const float*)d_in[9];
    const float* Wn2 = (const float*)d_in[10];
    const float* bn2 = (const float*)d_in[11];
    const float* Wh1 = (const float*)d_in[12];
    const float* bh1 = (const float*)d_in[13];
    const float* Wh2 = (const float*)d_in[14];
    const float* bh2 = (const float*)d_in[15];
    float* outp = (float*)d_out;

    char* ws = (char*)d_ws;
    float* tpart_ws = (float*)(ws + 0);          // 8*256 f = 8 KB
    float* agg_ws   = (float*)(ws + 8192);       // 256 f = 1 KB
    unsigned int* cnts = (unsigned int*)(ws + 10240);  // 2 counters

    // zero the barrier counters (captured, stream-ordered, replayed per-iter)
    (void)hipMemsetAsync((void*)cnts, 0, 16, stream);

    (void)hipFuncSetAttribute((const void*)fused_all,
                              hipFuncAttributeMaxDynamicSharedMemorySize,
                              F_SMEM_BYTES);

    hipLaunchKernelGGL(fused_all, dim3(64), dim3(256), F_SMEM_BYTES, stream,
                       positions, grid, W1, b1, W2, b2, W3, b3, Wn1, bn1,
                       Wn2, bn2, Wh1, bh1, Wh2, bh2,
                       tpart_ws, agg_ws, cnts, outp);
}

// Round 4
// 105.702 us; speedup vs baseline: 1.0825x; 1.0825x over previous
//
#include <hip/hip_runtime.h>

// ---------------------------------------------------------------------------
// Output depends ONLY on positions[0:64]. ~14M MACs total.
//
// R12: 5 small kernels. Evidence: R10 (3->2 kernels) = no change; R11
// (1 kernel + spin barriers) = +4.5us REGRESSION. So kernel boundaries are
// ~free and spins are bad -> use boundaries AS the cross-block sync and
// shrink per-CU staging bytes (the real cost @ ~10B/cyc/CU):
//  K1a (64 blk = bg x 8 col-slices): backbone replicated (argmin/h1/h2
//      verbatim) + gf for own (8 rows x 32 cols): W3 slice 16KB (was 128KB).
//  K1b (64 blk): R8 k2_tpart VERBATIM (Wn1 32KB slice + gf_ws 8KB) -> tpart.
//  K2  (32 blk): R11-proven agg slice (Wn2 8KB col-slice + tpart) -> agg_ws.
//  K3  (16 blk = 4 heads x 4 d-slices): heads h1 with Wh1 32KB slice
//      (was 128KB); per-output cc-chain identical -> h1h_ws.
//  K4  (4 blk): verbatim strictly-sequential final dot -> out.
//
// BIT-EXACTNESS: harness demands bit-exact (R1 failed by one ulp). Every
// per-output accumulation keeps the VERBATIM expression structure and
// ascending chunk order from rounds that scored absmax 0.0. Splitting is
// only along data-parallel output dims (cols/d), never along a reduction.
// f32 global round-trips are lossless. Do not reassociate; do not regroup.
// ---------------------------------------------------------------------------

__device__ __forceinline__ void async_cp16(const float* g, float* l) {
    __builtin_amdgcn_global_load_lds(
        (const __attribute__((address_space(1))) void*)g,
        (__attribute__((address_space(3))) void*)l, 16, 0, 0);
}
// contiguous: nfloats multiple of 256; 1 inst moves 256 floats (64 lanes x 16B)
__device__ __forceinline__ void stage_contig(const float* g, float* l, int nfloats, int tid) {
    const int lane = tid & 63, wv = tid >> 6;
    const int ninst = nfloats >> 8;
    for (int i = wv; i < ninst; i += 4)
        async_cp16(g + i*256 + lane*4, l + i*256);
}
// 32-col slice of row-major [nrows][ld] at col j0 -> LDS [r][32]
__device__ __forceinline__ void stage_slice32(const float* g, float* l, int ld, int j0, int nrows, int tid) {
    const int lane = tid & 63, wv = tid >> 6;
    const int r = lane >> 3, c4 = (lane & 7) << 2;
    const int ninst = nrows >> 3;
    for (int i = wv; i < ninst; i += 4)
        async_cp16(g + (i*8 + r)*ld + j0 + c4, l + i*256);
}

// ---- K1a (64 blocks = 8 row-groups x 8 col-slices): backbone + gf slice ---
__global__ __launch_bounds__(256) void k1a_gf(
    const float* __restrict__ positions, const float* __restrict__ grid_pts,
    const float* __restrict__ W1, const float* __restrict__ b1,
    const float* __restrict__ W2, const float* __restrict__ b2,
    const float* __restrict__ W3, const float* __restrict__ b3,
    float* __restrict__ gf_ws)                              // (64,256)
{
    __shared__ __align__(16) float w3s[128*32];             // 16 KB slice
    __shared__ float pos_s[192], grid_s[192], w1_s[192], b1_s[64];
    __shared__ int   idx_s[64], win_s[8];
    __shared__ __align__(16) float h1s[8*64];
    __shared__ __align__(16) float h2s[8*128];

    const int tid = threadIdx.x;
    const int blk = blockIdx.x;
    const int bg  = blk >> 3;          // rows bg*8 .. bg*8+7 (replicated x8)
    const int j0  = (blk & 7) * 32;    // own 32 output cols

    stage_slice32(W3, w3s, 256, j0, 128, tid);              // async at entry
    if (tid < 192) { pos_s[tid] = positions[tid]; grid_s[tid] = grid_pts[tid]; w1_s[tid] = W1[tid]; }
    if (tid >= 192) b1_s[tid - 192] = b1[tid - 192];
    const float bb2 = b2[tid & 127];
    __syncthreads();                                        // drains W3 slice

    if (tid < 64) {                      // verbatim argmin
        const float px = pos_s[tid*3], py = pos_s[tid*3+1], pz = pos_s[tid*3+2];
        float best = 3.4e38f; int bi = 0;
        for (int g = 0; g < 64; ++g) {
            const float dx = px - grid_s[g*3];
            const float dy = py - grid_s[g*3+1];
            const float dz = pz - grid_s[g*3+2];
            const float d2 = dx*dx + dy*dy + dz*dz;
            if (d2 < best) { best = d2; bi = g; }
        }
        idx_s[tid] = bi;
    }
    __syncthreads();
    if (tid < 8) {                       // verbatim winner rule, own 8 rows
        const int g = bg*8 + tid;
        int m = -1;
        for (int i = 0; i < 64; ++i) if (idx_s[i] == g) m = i;
        win_s[tid] = m;
    }
    __syncthreads();

    // h1 own 8 rows (512 outs): verbatim expression
    #pragma unroll
    for (int u = 0; u < 2; ++u) {
        const int e  = tid + u*256;
        const int lr = e >> 6, kk = e & 63;
        int r = win_s[lr]; if (r < 0) r = 0;
        const float acc = b1_s[kk] + pos_s[r*3]*w1_s[kk] + pos_s[r*3+1]*w1_s[64+kk]
                                   + pos_s[r*3+2]*w1_s[128+kk];
        h1s[lr*64 + kk] = fmaxf(acc, 0.f);
    }
    __syncthreads();

    // h2 own 8 rows: verbatim chunk structure; W2 via chunked GLOBAL loads
    {
        const int d = tid & 127, t0 = tid >> 7;
        float acc[4];
        #pragma unroll
        for (int m = 0; m < 4; ++m) acc[m] = bb2;
        for (int kc = 0; kc < 64; kc += 16) {
            float w[16];
            #pragma unroll
            for (int u = 0; u < 16; ++u) w[u] = W2[(kc+u)*128 + d];
            #pragma unroll
            for (int u = 0; u < 16; u += 4) {
                #pragma unroll
                for (int m = 0; m < 4; ++m) {
                    const float4 h4 = *(const float4*)&h1s[(t0 + 2*m)*64 + kc + u];
                    acc[m] += h4.x*w[u] + h4.y*w[u+1] + h4.z*w[u+2] + h4.w*w[u+3];
                }
            }
        }
        #pragma unroll
        for (int m = 0; m < 4; ++m)
            h2s[(t0 + 2*m)*128 + d] = fmaxf(acc[m], 0.f);
    }
    __syncthreads();

    // gf: one output (t, j0+jl) per thread; per-output chain VERBATIM
    {
        const int t = tid >> 5, jl = tid & 31;
        float ag = 0.f;
        for (int dc = 0; dc < 128; dc += 16) {
            float w[16];
            #pragma unroll
            for (int u = 0; u < 16; ++u) w[u] = w3s[(dc+u)*32 + jl];
            #pragma unroll
            for (int u = 0; u < 16; u += 4) {
                const float4 h4 = *(const float4*)&h2s[t*128 + dc + u];
                ag += h4.x*w[u] + h4.y*w[u+1] + h4.z*w[u+2] + h4.w*w[u+3];
            }
        }
        const float bb3 = b3[j0 + jl];
        gf_ws[(bg*8 + t)*256 + j0 + jl] = (win_s[t] >= 0) ? (ag + bb3) : 0.f;
    }
}

// ---- K1b (64 blocks): Wn1-slice tpart (R8 k2_tpart VERBATIM) -------------
__global__ __launch_bounds__(256) void k1b_tpart(
    const float* __restrict__ Wn1, const float* __restrict__ bn1,
    const float* __restrict__ gf_ws, float* __restrict__ tpart_ws)
{
    __shared__ __align__(16) float wn1_s[256*32];
    __shared__ __align__(16) float gf_s[8*256];
    __shared__ float r_s[256];

    const int tid = threadIdx.x;
    const int bg  = blockIdx.x >> 3;
    const int j0  = (blockIdx.x & 7) * 32;
    stage_slice32(Wn1, wn1_s, 256, j0, 256, tid);
    stage_contig(gf_ws + bg*8*256, gf_s, 8*256, tid);

    const int jl = tid & 31, t = tid >> 5;
    const float bb = bn1[j0 + jl];
    __syncthreads();

    float acc = bb;
    for (int cc = 0; cc < 256; cc += 32) {
        float w[32];
        #pragma unroll
        for (int u = 0; u < 32; ++u) w[u] = wn1_s[(cc+u)*32 + jl];
        #pragma unroll
        for (int u = 0; u < 32; u += 4) {
            const float4 g4 = *(const float4*)&gf_s[t*256 + cc + u];
            acc += g4.x*w[u] + g4.y*w[u+1] + g4.z*w[u+2] + g4.w*w[u+3];
        }
    }
    r_s[tid] = fmaxf(acc, 0.f);
    __syncthreads();
    if (t == 0) {
        float ps = 0.f;
        #pragma unroll
        for (int tt = 0; tt < 8; ++tt) ps += r_s[tt*32 + jl];
        tpart_ws[bg*256 + j0 + jl] = ps;
    }
}

// ---- K2 (32 blocks): tbar + agg 8-col slice (R11-proven bit-exact) -------
__global__ __launch_bounds__(256) void k2_agg(
    const float* __restrict__ Wn2, const float* __restrict__ bn2,
    const float* __restrict__ tpart_ws, float* __restrict__ agg_ws)
{
    __shared__ __align__(16) float wn2_s[256*8];            // 8 KB col-slice
    __shared__ __align__(16) float tp_s[2048];
    __shared__ __align__(16) float tbar_s[256];

    const int tid = threadIdx.x;
    const int j0a = blockIdx.x * 8;

    {   // Wn2 col-slice [256 rows][8 cols] at j0a -> wn2_s[r*8 + c]
        const int lane = tid & 63, wv = tid >> 6;
        const int r = lane >> 1, c4 = (lane & 1) << 2;
        for (int i = wv; i < 8; i += 4)
            async_cp16(Wn2 + (i*32 + r)*256 + j0a + c4, wn2_s + i*256);
    }
    stage_contig(tpart_ws, tp_s, 2048, tid);
    __syncthreads();

    {   // tbar: verbatim (q ascending, then *1/64)
        float tb = 0.f;
        #pragma unroll
        for (int q = 0; q < 8; ++q) tb += tp_s[q*256 + tid];
        tbar_s[tid] = tb * (1.f/64.f);
    }
    __syncthreads();

    if (tid < 8) {   // agg outputs j0a..j0a+7: verbatim chunk order
        float acc = bn2[j0a + tid];
        for (int jc = 0; jc < 256; jc += 32) {
            float w[32];
            #pragma unroll
            for (int u = 0; u < 32; ++u) w[u] = wn2_s[(jc+u)*8 + tid];
            #pragma unroll
            for (int u = 0; u < 32; u += 4) {
                const float4 t4 = *(const float4*)&tbar_s[jc + u];
                acc += t4.x*w[u] + t4.y*w[u+1] + t4.z*w[u+2] + t4.w*w[u+3];
            }
        }
        agg_ws[j0a + tid] = acc;
    }
}

// ---- K3 (16 blocks = 4 heads x 4 d-slices): heads h1 ---------------------
__global__ __launch_bounds__(256) void k3_h1(
    const float* __restrict__ Wh1, const float* __restrict__ bh1,
    const float* __restrict__ agg_ws, float* __restrict__ h1h_ws)
{
    __shared__ __align__(16) float whs[256*32];             // 32 KB slice
    __shared__ __align__(16) float agg_s[256];

    const int tid = threadIdx.x;
    const int k   = blockIdx.x >> 2;
    const int d0  = (blockIdx.x & 3) * 32;

    stage_slice32(Wh1 + k*32768, whs, 128, d0, 256, tid);
    agg_s[tid] = agg_ws[tid];
    __syncthreads();                                        // drains both

    if (tid < 32) {   // per-output cc-chain VERBATIM (cc ascending 0..255)
        const int dl = tid;
        float a = bh1[k*128 + d0 + dl];
        for (int cc = 0; cc < 256; cc += 16) {
            float wa[16];
            #pragma unroll
            for (int u = 0; u < 16; ++u) wa[u] = whs[(cc+u)*32 + dl];
            #pragma unroll
            for (int u = 0; u < 16; u += 4) {
                const float4 a4 = *(const float4*)&agg_s[cc + u];
                a += a4.x*wa[u] + a4.y*wa[u+1] + a4.z*wa[u+2] + a4.w*wa[u+3];
            }
        }
        h1h_ws[k*128 + d0 + dl] = fmaxf(a, 0.f);
    }
}

// ---- K4 (4 blocks): verbatim strictly-sequential final dot ---------------
__global__ __launch_bounds__(128) void k4_out(
    const float* __restrict__ Wh2, const float* __restrict__ bh2,
    const float* __restrict__ h1h_ws, float* __restrict__ out)
{
    __shared__ float hh_s[128], wh2_s[128];
    const int tid = threadIdx.x;
    const int k   = blockIdx.x;
    hh_s[tid]  = h1h_ws[k*128 + tid];
    wh2_s[tid] = Wh2[k*128 + tid];
    __syncthreads();
    if (tid == 0) {
        float a = bh2[k];
        for (int d = 0; d < 128; ++d) a += hh_s[d] * wh2_s[d];
        out[k] = a;
    }
}

extern "C" void kernel_launch(void* const* d_in, const int* in_sizes, int n_in,
                              void* d_out, int out_size, void* d_ws, size_t ws_size,
                              hipStream_t stream) {
    const float* positions = (const float*)d_in[0];
    const float* grid      = (const float*)d_in[1];
    const float* W1  = (const float*)d_in[2];
    const float* b1  = (const float*)d_in[3];
    const float* W2  = (const float*)d_in[4];
    const float* b2  = (const float*)d_in[5];
    const float* W3  = (const float*)d_in[6];
    const float* b3  = (const float*)d_in[7];
    const float* Wn1 = (const float*)d_in[8];
    const float* bn1 = (const float*)d_in[9];
    const float* Wn2 = (const float*)d_in[10];
    const float* bn2 = (const float*)d_in[11];
    const float* Wh1 = (const float*)d_in[12];
    const float* bh1 = (const float*)d_in[13];
    const float* Wh2 = (const float*)d_in[14];
    const float* bh2 = (const float*)d_in[15];
    float* out = (float*)d_out;

    char* ws = (char*)d_ws;                 // fully rewritten every call
    float* gf_ws    = (float*)(ws + 0);          // 64*256 f = 64 KB
    float* tpart_ws = (float*)(ws + 65536);      // 8*256 f = 8 KB
    float* agg_ws   = (float*)(ws + 73728);      // 256 f = 1 KB
    float* h1h_ws   = (float*)(ws + 74752);      // 4*128 f = 2 KB

    hipLaunchKernelGGL(k1a_gf,   dim3(64), dim3(256), 0, stream,
                       positions, grid, W1, b1, W2, b2, W3, b3, gf_ws);
    hipLaunchKernelGGL(k1b_tpart, dim3(64), dim3(256), 0, stream,
                       Wn1, bn1, gf_ws, tpart_ws);
    hipLaunchKernelGGL(k2_agg,   dim3(32), dim3(256), 0, stream,
                       Wn2, bn2, tpart_ws, agg_ws);
    hipLaunchKernelGGL(k3_h1,    dim3(16), dim3(256), 0, stream,
                       Wh1, bh1, agg_ws, h1h_ws);
    hipLaunchKernelGGL(k4_out,   dim3(4),  dim3(128), 0, stream,
                       Wh2, bh2, h1h_ws, out);
}

// Round 6
// 104.135 us; speedup vs baseline: 1.0988x; 1.0150x over previous
//
#include <hip/hip_runtime.h>

// ---------------------------------------------------------------------------
// Output depends ONLY on positions[0:64]. ~14M MACs total.
//
// R14 = R13 resubmitted verbatim (R13's bench died to an infra error:
// "MI355X container failed twice" — no pytest, no profile; kernel unjudged).
//
// R13: 4 kernels (was 5). Evidence so far: staging-byte cuts pay (R12 -4.2us);
// spin barriers regress (R11 +4.5us); boundaries cost ~2-2.5us each.
//  K1a (64 blk = bg x 8 col-slices): backbone replicated + gf 32-col slice.
//      W3 stage issued AFTER the first sync so its drain overlaps argmin.
//  K1b (128 blk = bg x 16 col-slices): tpart with 16-col Wn1 slices
//      (24KB staging/block, was 40KB). Per-output chains verbatim.
//  K2  (32 blk): tbar + agg 8-col slice (R11/R12-proven). Block0 zeroes the
//      K34 arrival counter (1 kernel boundary upstream of use -> visible).
//  K34 (16 blk = 4 heads x 4 d-slices): heads h1 verbatim; then LAST-ARRIVER
//      (threadfence + acq_rel fetch_add, NO spinning) computes the 4 final
//      strictly-sequential dots inline (one per thread, tid<4). K4 deleted.
//
// BIT-EXACTNESS: harness demands bit-exact (R1 failed by one ulp). Every
// per-output accumulation keeps the VERBATIM expression structure and
// ascending chunk order from rounds that scored absmax 0.0. Splits are only
// along data-parallel output dims; reduction orders (8-row groups, q 0..7,
// tt 0..7, cc/dc/jc ascending, final d 0..127 sequential) unchanged.
// f32 global round-trips are lossless. Do not reassociate; do not regroup.
// ---------------------------------------------------------------------------

__device__ __forceinline__ void async_cp16(const float* g, float* l) {
    __builtin_amdgcn_global_load_lds(
        (const __attribute__((address_space(1))) void*)g,
        (__attribute__((address_space(3))) void*)l, 16, 0, 0);
}
// contiguous: nfloats multiple of 256; 1 inst moves 256 floats (64 lanes x 16B)
__device__ __forceinline__ void stage_contig(const float* g, float* l, int nfloats, int tid) {
    const int lane = tid & 63, wv = tid >> 6;
    const int ninst = nfloats >> 8;
    for (int i = wv; i < ninst; i += 4)
        async_cp16(g + i*256 + lane*4, l + i*256);
}
// 32-col slice of row-major [nrows][ld] at col j0 -> LDS [r][32]
__device__ __forceinline__ void stage_slice32(const float* g, float* l, int ld, int j0, int nrows, int tid) {
    const int lane = tid & 63, wv = tid >> 6;
    const int r = lane >> 3, c4 = (lane & 7) << 2;
    const int ninst = nrows >> 3;
    for (int i = wv; i < ninst; i += 4)
        async_cp16(g + (i*8 + r)*ld + j0 + c4, l + i*256);
}
// 16-col slice of row-major [nrows][ld] at col j0 -> LDS [r][16]
__device__ __forceinline__ void stage_slice16(const float* g, float* l, int ld, int j0, int nrows, int tid) {
    const int lane = tid & 63, wv = tid >> 6;
    const int r = lane >> 2, c4 = (lane & 3) << 2;
    const int ninst = nrows >> 4;
    for (int i = wv; i < ninst; i += 4)
        async_cp16(g + (i*16 + r)*ld + j0 + c4, l + i*256);
}

// ---- K1a (64 blocks = 8 row-groups x 8 col-slices): backbone + gf slice ---
__global__ __launch_bounds__(256) void k1a_gf(
    const float* __restrict__ positions, const float* __restrict__ grid_pts,
    const float* __restrict__ W1, const float* __restrict__ b1,
    const float* __restrict__ W2, const float* __restrict__ b2,
    const float* __restrict__ W3, const float* __restrict__ b3,
    float* __restrict__ gf_ws)                              // (64,256)
{
    __shared__ __align__(16) float w3s[128*32];             // 16 KB slice
    __shared__ float pos_s[192], grid_s[192], w1_s[192], b1_s[64];
    __shared__ int   idx_s[64], win_s[8];
    __shared__ __align__(16) float h1s[8*64];
    __shared__ __align__(16) float h2s[8*128];

    const int tid = threadIdx.x;
    const int blk = blockIdx.x;
    const int bg  = blk >> 3;          // rows bg*8 .. bg*8+7 (replicated x8)
    const int j0  = (blk & 7) * 32;    // own 32 output cols

    if (tid < 192) { pos_s[tid] = positions[tid]; grid_s[tid] = grid_pts[tid]; w1_s[tid] = W1[tid]; }
    if (tid >= 192) b1_s[tid - 192] = b1[tid - 192];
    const float bb2 = b2[tid & 127];
    __syncthreads();                                        // small LDS only

    stage_slice32(W3, w3s, 256, j0, 128, tid);              // drains at next sync,
                                                            // overlapped w/ argmin
    if (tid < 64) {                      // verbatim argmin
        const float px = pos_s[tid*3], py = pos_s[tid*3+1], pz = pos_s[tid*3+2];
        float best = 3.4e38f; int bi = 0;
        for (int g = 0; g < 64; ++g) {
            const float dx = px - grid_s[g*3];
            const float dy = py - grid_s[g*3+1];
            const float dz = pz - grid_s[g*3+2];
            const float d2 = dx*dx + dy*dy + dz*dz;
            if (d2 < best) { best = d2; bi = g; }
        }
        idx_s[tid] = bi;
    }
    __syncthreads();
    if (tid < 8) {                       // verbatim winner rule, own 8 rows
        const int g = bg*8 + tid;
        int m = -1;
        for (int i = 0; i < 64; ++i) if (idx_s[i] == g) m = i;
        win_s[tid] = m;
    }
    __syncthreads();

    // h1 own 8 rows (512 outs): verbatim expression
    #pragma unroll
    for (int u = 0; u < 2; ++u) {
        const int e  = tid + u*256;
        const int lr = e >> 6, kk = e & 63;
        int r = win_s[lr]; if (r < 0) r = 0;
        const float acc = b1_s[kk] + pos_s[r*3]*w1_s[kk] + pos_s[r*3+1]*w1_s[64+kk]
                                   + pos_s[r*3+2]*w1_s[128+kk];
        h1s[lr*64 + kk] = fmaxf(acc, 0.f);
    }
    __syncthreads();

    // h2 own 8 rows: verbatim chunk structure; W2 via chunked GLOBAL loads
    {
        const int d = tid & 127, t0 = tid >> 7;
        float acc[4];
        #pragma unroll
        for (int m = 0; m < 4; ++m) acc[m] = bb2;
        for (int kc = 0; kc < 64; kc += 16) {
            float w[16];
            #pragma unroll
            for (int u = 0; u < 16; ++u) w[u] = W2[(kc+u)*128 + d];
            #pragma unroll
            for (int u = 0; u < 16; u += 4) {
                #pragma unroll
                for (int m = 0; m < 4; ++m) {
                    const float4 h4 = *(const float4*)&h1s[(t0 + 2*m)*64 + kc + u];
                    acc[m] += h4.x*w[u] + h4.y*w[u+1] + h4.z*w[u+2] + h4.w*w[u+3];
                }
            }
        }
        #pragma unroll
        for (int m = 0; m < 4; ++m)
            h2s[(t0 + 2*m)*128 + d] = fmaxf(acc[m], 0.f);
    }
    __syncthreads();

    // gf: one output (t, j0+jl) per thread; per-output chain VERBATIM
    {
        const int t = tid >> 5, jl = tid & 31;
        float ag = 0.f;
        for (int dc = 0; dc < 128; dc += 16) {
            float w[16];
            #pragma unroll
            for (int u = 0; u < 16; ++u) w[u] = w3s[(dc+u)*32 + jl];
            #pragma unroll
            for (int u = 0; u < 16; u += 4) {
                const float4 h4 = *(const float4*)&h2s[t*128 + dc + u];
                ag += h4.x*w[u] + h4.y*w[u+1] + h4.z*w[u+2] + h4.w*w[u+3];
            }
        }
        const float bb3 = b3[j0 + jl];
        gf_ws[(bg*8 + t)*256 + j0 + jl] = (win_s[t] >= 0) ? (ag + bb3) : 0.f;
    }
}

// ---- K1b (128 blocks = bg x 16 col-slices): Wn1-slice tpart --------------
__global__ __launch_bounds__(256) void k1b_tpart(
    const float* __restrict__ Wn1, const float* __restrict__ bn1,
    const float* __restrict__ gf_ws, float* __restrict__ tpart_ws)
{
    __shared__ __align__(16) float wn1_s[256*16];           // 16 KB slice
    __shared__ __align__(16) float gf_s[8*256];
    __shared__ float r_s[128];

    const int tid = threadIdx.x;
    const int bg  = blockIdx.x >> 4;
    const int j0  = (blockIdx.x & 15) * 16;
    stage_slice16(Wn1, wn1_s, 256, j0, 256, tid);
    stage_contig(gf_ws + bg*8*256, gf_s, 8*256, tid);

    const int jl = tid & 15, t = tid >> 4;                  // t in 0..15, rows use t<8
    const float bb = bn1[j0 + jl];
    __syncthreads();

    if (t < 8) {   // per-output (row t, col j0+jl) chain VERBATIM
        float acc = bb;
        for (int cc = 0; cc < 256; cc += 32) {
            float w[32];
            #pragma unroll
            for (int u = 0; u < 32; ++u) w[u] = wn1_s[(cc+u)*16 + jl];
            #pragma unroll
            for (int u = 0; u < 32; u += 4) {
                const float4 g4 = *(const float4*)&gf_s[t*256 + cc + u];
                acc += g4.x*w[u] + g4.y*w[u+1] + g4.z*w[u+2] + g4.w*w[u+3];
            }
        }
        r_s[t*16 + jl] = fmaxf(acc, 0.f);
    }
    __syncthreads();
    if (t == 0) {   // verbatim tt 0..7 ascending
        float ps = 0.f;
        #pragma unroll
        for (int tt = 0; tt < 8; ++tt) ps += r_s[tt*16 + jl];
        tpart_ws[bg*256 + j0 + jl] = ps;
    }
}

// ---- K2 (32 blocks): tbar + agg 8-col slice (proven bit-exact) -----------
__global__ __launch_bounds__(256) void k2_agg(
    const float* __restrict__ Wn2, const float* __restrict__ bn2,
    const float* __restrict__ tpart_ws, float* __restrict__ agg_ws,
    unsigned int* __restrict__ cnts)
{
    __shared__ __align__(16) float wn2_s[256*8];            // 8 KB col-slice
    __shared__ __align__(16) float tp_s[2048];
    __shared__ __align__(16) float tbar_s[256];

    const int tid = threadIdx.x;
    const int j0a = blockIdx.x * 8;

    if (blockIdx.x == 0 && tid == 0) cnts[0] = 0u;          // K34 counter; 1 full
                                                            // boundary downstream
    {   // Wn2 col-slice [256 rows][8 cols] at j0a -> wn2_s[r*8 + c]
        const int lane = tid & 63, wv = tid >> 6;
        const int r = lane >> 1, c4 = (lane & 1) << 2;
        for (int i = wv; i < 8; i += 4)
            async_cp16(Wn2 + (i*32 + r)*256 + j0a + c4, wn2_s + i*256);
    }
    stage_contig(tpart_ws, tp_s, 2048, tid);
    __syncthreads();

    {   // tbar: verbatim (q ascending, then *1/64)
        float tb = 0.f;
        #pragma unroll
        for (int q = 0; q < 8; ++q) tb += tp_s[q*256 + tid];
        tbar_s[tid] = tb * (1.f/64.f);
    }
    __syncthreads();

    if (tid < 8) {   // agg outputs j0a..j0a+7: verbatim chunk order
        float acc = bn2[j0a + tid];
        for (int jc = 0; jc < 256; jc += 32) {
            float w[32];
            #pragma unroll
            for (int u = 0; u < 32; ++u) w[u] = wn2_s[(jc+u)*8 + tid];
            #pragma unroll
            for (int u = 0; u < 32; u += 4) {
                const float4 t4 = *(const float4*)&tbar_s[jc + u];
                acc += t4.x*w[u] + t4.y*w[u+1] + t4.z*w[u+2] + t4.w*w[u+3];
            }
        }
        agg_ws[j0a + tid] = acc;
    }
}

// ---- K34 (16 blocks = 4 heads x 4 d-slices): heads h1 + last-arriver out --
__global__ __launch_bounds__(256) void k34_h1out(
    const float* __restrict__ Wh1, const float* __restrict__ bh1,
    const float* __restrict__ Wh2, const float* __restrict__ bh2,
    const float* __restrict__ agg_ws, float* __restrict__ h1h_ws,
    unsigned int* __restrict__ cnts, float* __restrict__ out)
{
    __shared__ __align__(16) float whs[256*32];             // 32 KB slice
    __shared__ __align__(16) float agg_s[256];
    __shared__ int last_s;

    const int tid = threadIdx.x;
    const int k   = blockIdx.x >> 2;
    const int d0  = (blockIdx.x & 3) * 32;

    stage_slice32(Wh1 + k*32768, whs, 128, d0, 256, tid);
    agg_s[tid] = agg_ws[tid];
    __syncthreads();                                        // drains both

    if (tid < 32) {   // per-output cc-chain VERBATIM (cc ascending 0..255)
        const int dl = tid;
        float a = bh1[k*128 + d0 + dl];
        for (int cc = 0; cc < 256; cc += 16) {
            float wa[16];
            #pragma unroll
            for (int u = 0; u < 16; ++u) wa[u] = whs[(cc+u)*32 + dl];
            #pragma unroll
            for (int u = 0; u < 16; u += 4) {
                const float4 a4 = *(const float4*)&agg_s[cc + u];
                a += a4.x*wa[u] + a4.y*wa[u+1] + a4.z*wa[u+2] + a4.w*wa[u+3];
            }
        }
        h1h_ws[k*128 + d0 + dl] = fmaxf(a, 0.f);
    }
    __threadfence();                     // release h1h stores device-wide
    __syncthreads();                     // all threads' fences complete
    if (tid == 0) {
        const unsigned old = __hip_atomic_fetch_add(
            &cnts[0], 1u, __ATOMIC_ACQ_REL, __HIP_MEMORY_SCOPE_AGENT);
        last_s = (old == 15u) ? 1 : 0;   // last arriver, no spinning
    }
    __syncthreads();
    if (last_s && tid < 4) {             // verbatim strictly-sequential dots
        const int kk = tid;
        float a = bh2[kk];
        for (int d = 0; d < 128; ++d)
            a += h1h_ws[kk*128 + d] * Wh2[kk*128 + d];
        out[kk] = a;
    }
}

extern "C" void kernel_launch(void* const* d_in, const int* in_sizes, int n_in,
                              void* d_out, int out_size, void* d_ws, size_t ws_size,
                              hipStream_t stream) {
    const float* positions = (const float*)d_in[0];
    const float* grid      = (const float*)d_in[1];
    const float* W1  = (const float*)d_in[2];
    const float* b1  = (const float*)d_in[3];
    const float* W2  = (const float*)d_in[4];
    const float* b2  = (const float*)d_in[5];
    const float* W3  = (const float*)d_in[6];
    const float* b3  = (const float*)d_in[7];
    const float* Wn1 = (const float*)d_in[8];
    const float* bn1 = (const float*)d_in[9];
    const float* Wn2 = (const float*)d_in[10];
    const float* bn2 = (const float*)d_in[11];
    const float* Wh1 = (const float*)d_in[12];
    const float* bh1 = (const float*)d_in[13];
    const float* Wh2 = (const float*)d_in[14];
    const float* bh2 = (const float*)d_in[15];
    float* out = (float*)d_out;

    char* ws = (char*)d_ws;                 // fully rewritten every call
    float* gf_ws    = (float*)(ws + 0);          // 64*256 f = 64 KB
    float* tpart_ws = (float*)(ws + 65536);      // 8*256 f = 8 KB
    float* agg_ws   = (float*)(ws + 73728);      // 256 f = 1 KB
    float* h1h_ws   = (float*)(ws + 74752);      // 4*128 f = 2 KB
    unsigned int* cnts = (unsigned int*)(ws + 76800);

    hipLaunchKernelGGL(k1a_gf,    dim3(64),  dim3(256), 0, stream,
                       positions, grid, W1, b1, W2, b2, W3, b3, gf_ws);
    hipLaunchKernelGGL(k1b_tpart, dim3(128), dim3(256), 0, stream,
                       Wn1, bn1, gf_ws, tpart_ws);
    hipLaunchKernelGGL(k2_agg,    dim3(32),  dim3(256), 0, stream,
                       Wn2, bn2, tpart_ws, agg_ws, cnts);
    hipLaunchKernelGGL(k34_h1out, dim3(16),  dim3(256), 0, stream,
                       Wh1, bh1, Wh2, bh2, agg_ws, h1h_ws, cnts, out);
}